// Round 1
// baseline (387.410 us; speedup 1.0000x reference)
//
#include <hip/hip_runtime.h>
#include <math.h>

#define Bb 4
#define Nn 384
#define CSs 384
#define Hh 12
#define Cc 16
#define PQq 4
#define PVv 8
#define FPROJ 1152
#define FCAT 576
#define INFV 100000.0f
#define EPSV 1e-8f

// ws layout (floats)
#define WS_PROJ 0
#define WS_QPTS (1536*1152)                 // 1,769,472
#define WS_KVPTS (WS_QPTS + 1536*144)       // 1,990,656
#define WS_CAT (WS_KVPTS + 1536*432)        // 2,654,208

// ---------------- Kernel 1: fused projection GEMM ----------------
// grid 192 blocks (8 rows each), 384 threads; each thread computes 3 columns x 8 rows
__global__ __launch_bounds__(384) void proj_kernel(
    const float* __restrict__ s,
    const float* __restrict__ w_q, const float* __restrict__ b_q,
    const float* __restrict__ w_kv, const float* __restrict__ b_kv,
    const float* __restrict__ w_qp, const float* __restrict__ b_qp,
    const float* __restrict__ w_kvp, const float* __restrict__ b_kvp,
    float* __restrict__ proj)
{
    __shared__ float sl[8][CSs];
    const int row0 = blockIdx.x * 8;
    const int t = threadIdx.x;
#pragma unroll
    for (int r = 0; r < 8; ++r) sl[r][t] = s[(size_t)(row0 + r) * CSs + t];
    __syncthreads();

    const float* wp0; const float* wp1; const float* wp2;
    int ld0, ld1, ld2; float bi0, bi1, bi2;
    {
        int f = t;
        if (f < 192)      { wp0 = w_q + f;         ld0 = 192; bi0 = b_q[f]; }
        else              { wp0 = w_kv + (f-192);  ld0 = 384; bi0 = b_kv[f-192]; }
    }
    {
        int f = t + 384;
        if (f < 576)      { wp1 = w_kv + (f-192);  ld1 = 384; bi1 = b_kv[f-192]; }
        else if (f < 720) { wp1 = w_qp + (f-576);  ld1 = 144; bi1 = b_qp[f-576]; }
        else              { wp1 = w_kvp + (f-720); ld1 = 432; bi1 = b_kvp[f-720]; }
    }
    {
        int f = t + 768;
        wp2 = w_kvp + (f-720); ld2 = 432; bi2 = b_kvp[f-720];
    }

    float a0[8] = {0,0,0,0,0,0,0,0};
    float a1[8] = {0,0,0,0,0,0,0,0};
    float a2[8] = {0,0,0,0,0,0,0,0};

    for (int d = 0; d < CSs; ++d) {
        float w0 = *wp0; wp0 += ld0;
        float w1 = *wp1; wp1 += ld1;
        float w2 = *wp2; wp2 += ld2;
#pragma unroll
        for (int r = 0; r < 8; ++r) {
            float sv = sl[r][d];
            a0[r] += sv * w0;
            a1[r] += sv * w1;
            a2[r] += sv * w2;
        }
    }
#pragma unroll
    for (int r = 0; r < 8; ++r) {
        float* pr = proj + (size_t)(row0 + r) * FPROJ;
        pr[t]       = a0[r] + bi0;
        pr[t + 384] = a1[r] + bi1;
        pr[t + 768] = a2[r] + bi2;
    }
}

// ---------------- Kernel 2: rigid apply ----------------
// grid 1536 blocks, 192 threads (one point each: 48 q_pts + 144 kv_pts)
__global__ __launch_bounds__(192) void rigid_kernel(
    const float* __restrict__ proj,
    const float* __restrict__ rot, const float* __restrict__ trans,
    float* __restrict__ qpts, float* __restrict__ kvpts)
{
    const int bn = blockIdx.x;
    const int t = threadIdx.x;
    const float* R = rot + (size_t)bn * 9;
    const float* T = trans + (size_t)bn * 3;
    const float r00=R[0], r01=R[1], r02=R[2];
    const float r10=R[3], r11=R[4], r12=R[5];
    const float r20=R[6], r21=R[7], r22=R[8];
    const float tx=T[0], ty=T[1], tz=T[2];
    const float* pr = proj + (size_t)bn * FPROJ;
    if (t < 48) {
        float x = pr[576 + t];
        float y = pr[576 + 48 + t];
        float z = pr[576 + 96 + t];
        float ox = r00*x + r01*y + r02*z + tx;
        float oy = r10*x + r11*y + r12*z + ty;
        float oz = r20*x + r21*y + r22*z + tz;
        float* o = qpts + (size_t)bn * 144 + t * 3;
        o[0] = ox; o[1] = oy; o[2] = oz;
    } else {
        int p = t - 48;
        float x = pr[720 + p];
        float y = pr[720 + 144 + p];
        float z = pr[720 + 288 + p];
        float ox = r00*x + r01*y + r02*z + tx;
        float oy = r10*x + r11*y + r12*z + ty;
        float oz = r20*x + r21*y + r22*z + tz;
        float* o = kvpts + (size_t)bn * 432 + p * 3;
        o[0] = ox; o[1] = oy; o[2] = oz;
    }
}

// ---------------- Kernel 3: attention ----------------
// grid = B*H*(N/4) = 4608 blocks, 256 threads; wave w handles row i0+w
__global__ __launch_bounds__(256) void attn_kernel(
    const float* __restrict__ proj,
    const float* __restrict__ qpts, const float* __restrict__ kvpts,
    const float* __restrict__ rot, const float* __restrict__ trans,
    const float* __restrict__ mask, const float* __restrict__ head_weights,
    float* __restrict__ cat)
{
    __shared__ float logits[4][Nn];
    const int bid = blockIdx.x;
    const int i0 = (bid % (Nn/4)) * 4;
    const int h  = (bid / (Nn/4)) % Hh;
    const int b  = bid / ((Nn/4) * Hh);
    const int w = threadIdx.x >> 6;
    const int lane = threadIdx.x & 63;
    const int i = i0 + w;
    const int bnI = b * Nn + i;

    const float* qrow = proj + (size_t)bnI * FPROJ + h * Cc;
    float qv[16];
#pragma unroll
    for (int c = 0; c < 16; ++c) qv[c] = qrow[c];
    const float* qp = qpts + (size_t)bnI * 144 + h * 12;
    float qpv[12];
#pragma unroll
    for (int tt = 0; tt < 12; ++tt) qpv[tt] = qp[tt];

    const float hw = log1pf(expf(head_weights[h]));           // softplus
    const float wc = -0.5f * hw * 0.13608276348795434f;       // * sqrt(1/54)
    const float scale2 = 2.0f * 0.14433756729740643f;         // 2 * sqrt(1/48)
    const float mi = mask[b * Nn + i];

    const float* kb  = proj  + (size_t)(b * Nn) * FPROJ + 192 + h * 32;
    const float* kpb = kvpts + (size_t)(b * Nn) * 432 + h * 36;
    const float* mb  = mask + b * Nn;

    float mmax = -3.0e38f;
#pragma unroll
    for (int jj = 0; jj < 6; ++jj) {
        int j = jj * 64 + lane;
        const float* kp = kb + (size_t)j * FPROJ;
        float dot = 0.0f;
#pragma unroll
        for (int c = 0; c < 16; ++c) dot += qv[c] * kp[c];
        const float* kpp = kpb + (size_t)j * 432;
        float sq = 0.0f;
#pragma unroll
        for (int tt = 0; tt < 12; ++tt) { float d = qpv[tt] - kpp[tt]; sq += d * d; }
        float logit = scale2 * dot + wc * sq + INFV * (mi * mb[j] - 1.0f);
        logits[w][j] = logit;
        mmax = fmaxf(mmax, logit);
    }
    __syncthreads();

#pragma unroll
    for (int off = 32; off >= 1; off >>= 1) mmax = fmaxf(mmax, __shfl_xor(mmax, off));

    float ssum = 0.0f;
    float acc[16]; float accp[24];
#pragma unroll
    for (int c = 0; c < 16; ++c) acc[c] = 0.0f;
#pragma unroll
    for (int tt = 0; tt < 24; ++tt) accp[tt] = 0.0f;

#pragma unroll
    for (int jj = 0; jj < 6; ++jj) {
        int j = jj * 64 + lane;
        float a = expf(logits[w][j] - mmax);
        ssum += a;
        const float* vp = kb + (size_t)j * FPROJ + 16;
#pragma unroll
        for (int c = 0; c < 16; ++c) acc[c] += a * vp[c];
        const float* vpp = kpb + (size_t)j * 432 + 12;
#pragma unroll
        for (int tt = 0; tt < 24; ++tt) accp[tt] += a * vpp[tt];
    }

#pragma unroll
    for (int off = 32; off >= 1; off >>= 1) {
        ssum += __shfl_xor(ssum, off);
#pragma unroll
        for (int c = 0; c < 16; ++c) acc[c] += __shfl_xor(acc[c], off);
#pragma unroll
        for (int tt = 0; tt < 24; ++tt) accp[tt] += __shfl_xor(accp[tt], off);
    }

    const float inv = 1.0f / ssum;
    const float* R = rot + (size_t)bnI * 9;
    const float* T = trans + (size_t)bnI * 3;
    float* crow = cat + (size_t)bnI * FCAT;

#pragma unroll
    for (int c = 0; c < 16; ++c) {
        if (lane == c) crow[h * 16 + c] = acc[c] * inv;
    }
#pragma unroll
    for (int p = 0; p < 8; ++p) {
        if (lane == p) {
            float g0 = accp[p*3+0] * inv - T[0];
            float g1 = accp[p*3+1] * inv - T[1];
            float g2 = accp[p*3+2] * inv - T[2];
            float lx = R[0]*g0 + R[3]*g1 + R[6]*g2;
            float ly = R[1]*g0 + R[4]*g1 + R[7]*g2;
            float lz = R[2]*g0 + R[5]*g1 + R[8]*g2;
            crow[192 + h*8 + p] = lx;
            crow[288 + h*8 + p] = ly;
            crow[384 + h*8 + p] = lz;
            crow[480 + h*8 + p] = sqrtf(lx*lx + ly*ly + lz*lz + EPSV);
        }
    }
}

// ---------------- Kernel 4: output GEMM ----------------
// grid 256 blocks (6 rows each), 384 threads
__global__ __launch_bounds__(384) void out_kernel(
    const float* __restrict__ cat,
    const float* __restrict__ w_out, const float* __restrict__ b_out,
    float* __restrict__ out)
{
    __shared__ float cl[6][FCAT];
    const int row0 = blockIdx.x * 6;
    const int t = threadIdx.x;
    for (int idx = t; idx < 6 * FCAT; idx += 384) {
        cl[idx / FCAT][idx % FCAT] = cat[(size_t)row0 * FCAT + idx];
    }
    __syncthreads();
    float acc[6] = {0,0,0,0,0,0};
    const float* wp = w_out + t;
    for (int d = 0; d < FCAT; ++d) {
        float wv = wp[(size_t)d * 384];
#pragma unroll
        for (int r = 0; r < 6; ++r) acc[r] += cl[r][d] * wv;
    }
    const float bb = b_out[t];
#pragma unroll
    for (int r = 0; r < 6; ++r) out[(size_t)(row0 + r) * 384 + t] = acc[r] + bb;
}

extern "C" void kernel_launch(void* const* d_in, const int* in_sizes, int n_in,
                              void* d_out, int out_size, void* d_ws, size_t ws_size,
                              hipStream_t stream) {
    const float* s     = (const float*)d_in[0];
    const float* rot   = (const float*)d_in[2];
    const float* trans = (const float*)d_in[3];
    const float* mask  = (const float*)d_in[4];
    const float* w_q   = (const float*)d_in[5];
    const float* b_q   = (const float*)d_in[6];
    const float* w_kv  = (const float*)d_in[7];
    const float* b_kv  = (const float*)d_in[8];
    const float* w_qp  = (const float*)d_in[13];
    const float* b_qp  = (const float*)d_in[14];
    const float* w_kvp = (const float*)d_in[15];
    const float* b_kvp = (const float*)d_in[16];
    const float* hwts  = (const float*)d_in[17];
    const float* w_out = (const float*)d_in[18];
    const float* b_out = (const float*)d_in[19];

    float* ws    = (float*)d_ws;
    float* proj  = ws + WS_PROJ;
    float* qpts  = ws + WS_QPTS;
    float* kvpts = ws + WS_KVPTS;
    float* catb  = ws + WS_CAT;
    float* out   = (float*)d_out;

    hipLaunchKernelGGL(proj_kernel, dim3(192), dim3(384), 0, stream,
                       s, w_q, b_q, w_kv, b_kv, w_qp, b_qp, w_kvp, b_kvp, proj);
    hipLaunchKernelGGL(rigid_kernel, dim3(1536), dim3(192), 0, stream,
                       proj, rot, trans, qpts, kvpts);
    hipLaunchKernelGGL(attn_kernel, dim3(4608), dim3(256), 0, stream,
                       proj, qpts, kvpts, rot, trans, mask, hwts, catb);
    hipLaunchKernelGGL(out_kernel, dim3(256), dim3(384), 0, stream,
                       catb, w_out, b_out, out);
}

// Round 2
// 266.473 us; speedup vs baseline: 1.4538x; 1.4538x over previous
//
#include <hip/hip_runtime.h>
#include <math.h>

#define Bb 4
#define Nn 384
#define CSs 384
#define Hh 12
#define Cc 16
#define PQq 4
#define PVv 8
#define FPROJ 1152
#define FCAT 576
#define INFV 100000.0f
#define EPSV 1e-8f
#define JT 128

// ws layout (floats)
#define WS_PROJ 0
#define WS_KP   (1536*1152)             // 1,769,472
#define WS_VP   (WS_KP + 48*384*16)     // 2,064,384
#define WS_KPP  (WS_VP + 48*384*16)     // 2,359,296
#define WS_VPP  (WS_KPP + 48*384*12)    // 2,580,480
#define WS_CAT  (WS_VPP + 48*384*24)    // 3,022,848
// end: 3,907,584 floats = 15.63 MB

// ---------------- Kernel 1: fused projection GEMM ----------------
__global__ __launch_bounds__(384) void proj_kernel(
    const float* __restrict__ s,
    const float* __restrict__ w_q, const float* __restrict__ b_q,
    const float* __restrict__ w_kv, const float* __restrict__ b_kv,
    const float* __restrict__ w_qp, const float* __restrict__ b_qp,
    const float* __restrict__ w_kvp, const float* __restrict__ b_kvp,
    float* __restrict__ proj)
{
    __shared__ float sl[8][CSs];
    const int row0 = blockIdx.x * 8;
    const int t = threadIdx.x;
#pragma unroll
    for (int r = 0; r < 8; ++r) sl[r][t] = s[(size_t)(row0 + r) * CSs + t];
    __syncthreads();

    const float* wp0; const float* wp1; const float* wp2;
    int ld0, ld1, ld2; float bi0, bi1, bi2;
    {
        int f = t;
        if (f < 192)      { wp0 = w_q + f;         ld0 = 192; bi0 = b_q[f]; }
        else              { wp0 = w_kv + (f-192);  ld0 = 384; bi0 = b_kv[f-192]; }
    }
    {
        int f = t + 384;
        if (f < 576)      { wp1 = w_kv + (f-192);  ld1 = 384; bi1 = b_kv[f-192]; }
        else if (f < 720) { wp1 = w_qp + (f-576);  ld1 = 144; bi1 = b_qp[f-576]; }
        else              { wp1 = w_kvp + (f-720); ld1 = 432; bi1 = b_kvp[f-720]; }
    }
    {
        int f = t + 768;
        wp2 = w_kvp + (f-720); ld2 = 432; bi2 = b_kvp[f-720];
    }

    float a0[8] = {0,0,0,0,0,0,0,0};
    float a1[8] = {0,0,0,0,0,0,0,0};
    float a2[8] = {0,0,0,0,0,0,0,0};

    for (int d = 0; d < CSs; ++d) {
        float w0 = *wp0; wp0 += ld0;
        float w1 = *wp1; wp1 += ld1;
        float w2 = *wp2; wp2 += ld2;
#pragma unroll
        for (int r = 0; r < 8; ++r) {
            float sv = sl[r][d];
            a0[r] += sv * w0;
            a1[r] += sv * w1;
            a2[r] += sv * w2;
        }
    }
#pragma unroll
    for (int r = 0; r < 8; ++r) {
        float* pr = proj + (size_t)(row0 + r) * FPROJ;
        pr[t]       = a0[r] + bi0;
        pr[t + 384] = a1[r] + bi1;
        pr[t + 768] = a2[r] + bi2;
    }
}

// ---------------- Kernel 2: rigid-apply + pack K/V/kpts/vpts ----------------
// grid 1536 blocks (one bn each), 192 threads
__global__ __launch_bounds__(192) void pack_kernel(
    const float* __restrict__ proj,
    const float* __restrict__ rot, const float* __restrict__ trans,
    float* __restrict__ Kp, float* __restrict__ Vp,
    float* __restrict__ KPp, float* __restrict__ VPp)
{
    const int bn = blockIdx.x;
    const int b = bn / Nn;
    const int n = bn % Nn;
    const int t = threadIdx.x;
    const float* R = rot + (size_t)bn * 9;
    const float* T = trans + (size_t)bn * 3;
    const float* pr = proj + (size_t)bn * FPROJ;

    if (t < 144) {
        // kv point t: h = t/12, pp = t%12; pp<4 -> k_pt, else v_pt
        float x = pr[720 + t];
        float y = pr[720 + 144 + t];
        float z = pr[720 + 288 + t];
        float ox = R[0]*x + R[1]*y + R[2]*z + T[0];
        float oy = R[3]*x + R[4]*y + R[5]*z + T[1];
        float oz = R[6]*x + R[7]*y + R[8]*z + T[2];
        int h = t / 12, pp = t % 12;
        int bh = b * Hh + h;
        if (pp < PQq) {
            float* o = KPp + ((size_t)(bh * Nn + n)) * 12 + pp * 3;
            o[0] = ox; o[1] = oy; o[2] = oz;
        } else {
            float* o = VPp + ((size_t)(bh * Nn + n)) * 24 + (pp - PQq) * 3;
            o[0] = ox; o[1] = oy; o[2] = oz;
        }
    }
#pragma unroll
    for (int rep = 0; rep < 2; ++rep) {
        int idx = t + rep * 192;           // 0..383
        int h = idx / 32, c2 = idx % 32;
        int bh = b * Hh + h;
        float v = pr[192 + h * 32 + c2];
        if (c2 < 16) Kp[((size_t)(bh * Nn + n)) * 16 + c2] = v;
        else         Vp[((size_t)(bh * Nn + n)) * 16 + (c2 - 16)] = v;
    }
}

// ---------------- Kernel 3: attention (LDS-staged, transposed tiles) ----------------
// grid = B*H*(N/8) = 2304 blocks, 512 threads (8 waves); wave w -> row i0+w
__global__ __launch_bounds__(512) void attn_kernel(
    const float* __restrict__ proj,
    const float* __restrict__ Kp, const float* __restrict__ Vp,
    const float* __restrict__ KPp, const float* __restrict__ VPp,
    const float* __restrict__ rot, const float* __restrict__ trans,
    const float* __restrict__ mask, const float* __restrict__ head_weights,
    float* __restrict__ cat)
{
    __shared__ float lg[8][Nn];      // 12 KB logits
    __shared__ float st[5120];       // 20 KB stage (union)

    const int bid = blockIdx.x;
    const int ib = bid % (Nn / 8);
    const int h  = (bid / (Nn / 8)) % Hh;
    const int b  = bid / ((Nn / 8) * Hh);
    const int tid = threadIdx.x;
    const int w = tid >> 6;
    const int lane = tid & 63;
    const int i = ib * 8 + w;
    const int bnI = b * Nn + i;
    const int bh = b * Hh + h;

    // q row
    const float* qrow = proj + (size_t)bnI * FPROJ + h * Cc;
    float qv[16];
#pragma unroll
    for (int c = 0; c < 16; ++c) qv[c] = qrow[c];

    // q_pts: rigid-apply in registers (cols p, 48+p, 96+p of qp block; p = h*4+pq)
    const float* R = rot + (size_t)bnI * 9;
    const float* T = trans + (size_t)bnI * 3;
    float qpv[12];
    {
        const float* pq = proj + (size_t)bnI * FPROJ + 576;
#pragma unroll
        for (int p = 0; p < PQq; ++p) {
            float x = pq[h * PQq + p];
            float y = pq[48 + h * PQq + p];
            float z = pq[96 + h * PQq + p];
            qpv[p*3+0] = R[0]*x + R[1]*y + R[2]*z + T[0];
            qpv[p*3+1] = R[3]*x + R[4]*y + R[5]*z + T[1];
            qpv[p*3+2] = R[6]*x + R[7]*y + R[8]*z + T[2];
        }
    }

    const float hw = log1pf(expf(head_weights[h]));
    const float wc = -0.5f * hw * 0.13608276348795434f;   // * sqrt(1/54)
    const float scale2 = 2.0f * 0.14433756729740643f;     // 2 * sqrt(1/48)
    const float mi = mask[b * Nn + i];
    const float* mb = mask + b * Nn;

    const float* KpB  = Kp  + (size_t)(bh * Nn) * 16;
    const float* VpB  = Vp  + (size_t)(bh * Nn) * 16;
    const float* KPpB = KPp + (size_t)(bh * Nn) * 12;
    const float* VPpB = VPp + (size_t)(bh * Nn) * 24;

    float mmax = -3.0e38f;

    // ---------- pass 1: logits ----------
    for (int tile = 0; tile < Nn / JT; ++tile) {
        // stage K (transposed): 2048 floats = 512 float4, thread t -> j=t>>2, cq=t&3
        {
            int j = tid >> 2, cq = tid & 3;
            const float4 v = *(const float4*)(KpB + ((size_t)(tile * JT + j)) * 16 + cq * 4);
            st[(cq*4+0)*JT + j] = v.x;
            st[(cq*4+1)*JT + j] = v.y;
            st[(cq*4+2)*JT + j] = v.z;
            st[(cq*4+3)*JT + j] = v.w;
        }
        // stage KP (transposed): 1536 floats = 384 float4
        if (tid < 384) {
            int j = tid / 3, cp = tid % 3;
            const float4 v = *(const float4*)(KPpB + ((size_t)(tile * JT + j)) * 12 + cp * 4);
            st[2048 + (cp*4+0)*JT + j] = v.x;
            st[2048 + (cp*4+1)*JT + j] = v.y;
            st[2048 + (cp*4+2)*JT + j] = v.z;
            st[2048 + (cp*4+3)*JT + j] = v.w;
        }
        __syncthreads();
#pragma unroll
        for (int l2 = 0; l2 < 2; ++l2) {
            int jj = l2 * 64 + lane;
            int j = tile * JT + jj;
            float dot = 0.0f;
#pragma unroll
            for (int c = 0; c < 16; ++c) dot += qv[c] * st[c * JT + jj];
            float sq = 0.0f;
#pragma unroll
            for (int tt = 0; tt < 12; ++tt) {
                float d = qpv[tt] - st[2048 + tt * JT + jj];
                sq += d * d;
            }
            float logit = scale2 * dot + wc * sq + INFV * (mi * mb[j] - 1.0f);
            lg[w][j] = logit;
            mmax = fmaxf(mmax, logit);
        }
        __syncthreads();
    }

#pragma unroll
    for (int off = 32; off >= 1; off >>= 1) mmax = fmaxf(mmax, __shfl_xor(mmax, off));

    // ---------- pass 2: weighted sums ----------
    float ssum = 0.0f;
    float acc[16]; float accp[24];
#pragma unroll
    for (int c = 0; c < 16; ++c) acc[c] = 0.0f;
#pragma unroll
    for (int tt = 0; tt < 24; ++tt) accp[tt] = 0.0f;

    for (int tile = 0; tile < Nn / JT; ++tile) {
        {
            int j = tid >> 2, cq = tid & 3;
            const float4 v = *(const float4*)(VpB + ((size_t)(tile * JT + j)) * 16 + cq * 4);
            st[(cq*4+0)*JT + j] = v.x;
            st[(cq*4+1)*JT + j] = v.y;
            st[(cq*4+2)*JT + j] = v.z;
            st[(cq*4+3)*JT + j] = v.w;
        }
        // stage VP: 3072 floats = 768 float4 in two rounds
#pragma unroll
        for (int rep = 0; rep < 2; ++rep) {
            int e = tid + rep * 512;
            if (e < 768) {
                int j = e / 6, cp = e % 6;
                const float4 v = *(const float4*)(VPpB + ((size_t)(tile * JT + j)) * 24 + cp * 4);
                st[2048 + (cp*4+0)*JT + j] = v.x;
                st[2048 + (cp*4+1)*JT + j] = v.y;
                st[2048 + (cp*4+2)*JT + j] = v.z;
                st[2048 + (cp*4+3)*JT + j] = v.w;
            }
        }
        __syncthreads();
#pragma unroll
        for (int l2 = 0; l2 < 2; ++l2) {
            int jj = l2 * 64 + lane;
            int j = tile * JT + jj;
            float a = __expf(lg[w][j] - mmax);
            ssum += a;
#pragma unroll
            for (int c = 0; c < 16; ++c) acc[c] += a * st[c * JT + jj];
#pragma unroll
            for (int p = 0; p < 24; ++p) accp[p] += a * st[2048 + p * JT + jj];
        }
        __syncthreads();
    }

#pragma unroll
    for (int off = 32; off >= 1; off >>= 1) {
        ssum += __shfl_xor(ssum, off);
#pragma unroll
        for (int c = 0; c < 16; ++c) acc[c] += __shfl_xor(acc[c], off);
#pragma unroll
        for (int tt = 0; tt < 24; ++tt) accp[tt] += __shfl_xor(accp[tt], off);
    }

    const float inv = 1.0f / ssum;
    float* crow = cat + (size_t)bnI * FCAT;

#pragma unroll
    for (int c = 0; c < 16; ++c) {
        if (lane == c) crow[h * 16 + c] = acc[c] * inv;
    }
#pragma unroll
    for (int p = 0; p < 8; ++p) {
        if (lane == p) {
            float g0 = accp[p*3+0] * inv - T[0];
            float g1 = accp[p*3+1] * inv - T[1];
            float g2 = accp[p*3+2] * inv - T[2];
            float lx = R[0]*g0 + R[3]*g1 + R[6]*g2;
            float ly = R[1]*g0 + R[4]*g1 + R[7]*g2;
            float lz = R[2]*g0 + R[5]*g1 + R[8]*g2;
            crow[192 + h*8 + p] = lx;
            crow[288 + h*8 + p] = ly;
            crow[384 + h*8 + p] = lz;
            crow[480 + h*8 + p] = sqrtf(lx*lx + ly*ly + lz*lz + EPSV);
        }
    }
}

// ---------------- Kernel 4: output GEMM ----------------
__global__ __launch_bounds__(384) void out_kernel(
    const float* __restrict__ cat,
    const float* __restrict__ w_out, const float* __restrict__ b_out,
    float* __restrict__ out)
{
    __shared__ float cl[6][FCAT];
    const int row0 = blockIdx.x * 6;
    const int t = threadIdx.x;
    for (int idx = t; idx < 6 * FCAT; idx += 384) {
        cl[idx / FCAT][idx % FCAT] = cat[(size_t)row0 * FCAT + idx];
    }
    __syncthreads();
    float acc[6] = {0,0,0,0,0,0};
    const float* wp = w_out + t;
    for (int d = 0; d < FCAT; ++d) {
        float wv = wp[(size_t)d * 384];
#pragma unroll
        for (int r = 0; r < 6; ++r) acc[r] += cl[r][d] * wv;
    }
    const float bb = b_out[t];
#pragma unroll
    for (int r = 0; r < 6; ++r) out[(size_t)(row0 + r) * 384 + t] = acc[r] + bb;
}

extern "C" void kernel_launch(void* const* d_in, const int* in_sizes, int n_in,
                              void* d_out, int out_size, void* d_ws, size_t ws_size,
                              hipStream_t stream) {
    const float* s     = (const float*)d_in[0];
    const float* rot   = (const float*)d_in[2];
    const float* trans = (const float*)d_in[3];
    const float* mask  = (const float*)d_in[4];
    const float* w_q   = (const float*)d_in[5];
    const float* b_q   = (const float*)d_in[6];
    const float* w_kv  = (const float*)d_in[7];
    const float* b_kv  = (const float*)d_in[8];
    const float* w_qp  = (const float*)d_in[13];
    const float* b_qp  = (const float*)d_in[14];
    const float* w_kvp = (const float*)d_in[15];
    const float* b_kvp = (const float*)d_in[16];
    const float* hwts  = (const float*)d_in[17];
    const float* w_out = (const float*)d_in[18];
    const float* b_out = (const float*)d_in[19];

    float* ws    = (float*)d_ws;
    float* proj  = ws + WS_PROJ;
    float* Kp    = ws + WS_KP;
    float* Vp    = ws + WS_VP;
    float* KPp   = ws + WS_KPP;
    float* VPp   = ws + WS_VPP;
    float* catb  = ws + WS_CAT;
    float* out   = (float*)d_out;

    hipLaunchKernelGGL(proj_kernel, dim3(192), dim3(384), 0, stream,
                       s, w_q, b_q, w_kv, b_kv, w_qp, b_qp, w_kvp, b_kvp, proj);
    hipLaunchKernelGGL(pack_kernel, dim3(1536), dim3(192), 0, stream,
                       proj, rot, trans, Kp, Vp, KPp, VPp);
    hipLaunchKernelGGL(attn_kernel, dim3(2304), dim3(512), 0, stream,
                       proj, Kp, Vp, KPp, VPp, rot, trans, mask, hwts, catb);
    hipLaunchKernelGGL(out_kernel, dim3(256), dim3(384), 0, stream,
                       catb, w_out, b_out, out);
}

// Round 3
// 156.261 us; speedup vs baseline: 2.4793x; 1.7053x over previous
//
#include <hip/hip_runtime.h>
#include <math.h>

#define Bb 4
#define Nn 384
#define CSs 384
#define Hh 12
#define Cc 16
#define PQq 4
#define PVv 8
#define FPROJ 1152
#define FCAT 576
#define INFV 100000.0f
#define EPSV 1e-8f
#define JT 128

// ws layout (floats)
#define WS_PROJ 0
#define WS_KP   (1536*1152)             // 1,769,472
#define WS_VP   (WS_KP + 48*384*16)     // 2,064,384
#define WS_KPP  (WS_VP + 48*384*16)     // 2,359,296
#define WS_VPP  (WS_KPP + 48*384*12)    // 2,580,480
#define WS_CAT  (WS_VPP + 48*384*24)    // 3,022,848
// end: 3,907,584 floats = 15.63 MB

// ---------------- Kernel 1: fused projection GEMM (scalar-s, no LDS) ----------------
__global__ __launch_bounds__(384) void proj_kernel(
    const float* __restrict__ s,
    const float* __restrict__ w_q, const float* __restrict__ b_q,
    const float* __restrict__ w_kv, const float* __restrict__ b_kv,
    const float* __restrict__ w_qp, const float* __restrict__ b_qp,
    const float* __restrict__ w_kvp, const float* __restrict__ b_kvp,
    float* __restrict__ proj)
{
    const int row0 = blockIdx.x * 8;
    const int t = threadIdx.x;

    const float* wp0; const float* wp1; const float* wp2;
    int ld0, ld1, ld2; float bi0, bi1, bi2;
    {
        int f = t;
        if (f < 192)      { wp0 = w_q + f;         ld0 = 192; bi0 = b_q[f]; }
        else              { wp0 = w_kv + (f-192);  ld0 = 384; bi0 = b_kv[f-192]; }
    }
    {
        int f = t + 384;
        if (f < 576)      { wp1 = w_kv + (f-192);  ld1 = 384; bi1 = b_kv[f-192]; }
        else if (f < 720) { wp1 = w_qp + (f-576);  ld1 = 144; bi1 = b_qp[f-576]; }
        else              { wp1 = w_kvp + (f-720); ld1 = 432; bi1 = b_kvp[f-720]; }
    }
    {
        int f = t + 768;
        wp2 = w_kvp + (f-720); ld2 = 432; bi2 = b_kvp[f-720];
    }

    float a0[8] = {0,0,0,0,0,0,0,0};
    float a1[8] = {0,0,0,0,0,0,0,0};
    float a2[8] = {0,0,0,0,0,0,0,0};

    const float* s0 = s + (size_t)row0 * CSs;

    for (int d = 0; d < CSs; d += 4) {
        float4 sv[8];
#pragma unroll
        for (int r = 0; r < 8; ++r)
            sv[r] = *(const float4*)(s0 + (size_t)r * CSs + d);   // uniform addr -> s_load
#pragma unroll
        for (int dd = 0; dd < 4; ++dd) {
            float w0 = *wp0; wp0 += ld0;
            float w1 = *wp1; wp1 += ld1;
            float w2 = *wp2; wp2 += ld2;
#pragma unroll
            for (int r = 0; r < 8; ++r) {
                float svv = ((const float*)&sv[r])[dd];
                a0[r] += svv * w0;
                a1[r] += svv * w1;
                a2[r] += svv * w2;
            }
        }
    }
#pragma unroll
    for (int r = 0; r < 8; ++r) {
        float* pr = proj + (size_t)(row0 + r) * FPROJ;
        pr[t]       = a0[r] + bi0;
        pr[t + 384] = a1[r] + bi1;
        pr[t + 768] = a2[r] + bi2;
    }
}

// ---------------- Kernel 2: rigid-apply + pack K/V/kpts/vpts ----------------
__global__ __launch_bounds__(192) void pack_kernel(
    const float* __restrict__ proj,
    const float* __restrict__ rot, const float* __restrict__ trans,
    float* __restrict__ Kp, float* __restrict__ Vp,
    float* __restrict__ KPp, float* __restrict__ VPp)
{
    const int bn = blockIdx.x;
    const int b = bn / Nn;
    const int n = bn % Nn;
    const int t = threadIdx.x;
    const float* R = rot + (size_t)bn * 9;
    const float* T = trans + (size_t)bn * 3;
    const float* pr = proj + (size_t)bn * FPROJ;

    if (t < 144) {
        float x = pr[720 + t];
        float y = pr[720 + 144 + t];
        float z = pr[720 + 288 + t];
        float ox = R[0]*x + R[1]*y + R[2]*z + T[0];
        float oy = R[3]*x + R[4]*y + R[5]*z + T[1];
        float oz = R[6]*x + R[7]*y + R[8]*z + T[2];
        int h = t / 12, pp = t % 12;
        int bh = b * Hh + h;
        if (pp < PQq) {
            float* o = KPp + ((size_t)(bh * Nn + n)) * 12 + pp * 3;
            o[0] = ox; o[1] = oy; o[2] = oz;
        } else {
            float* o = VPp + ((size_t)(bh * Nn + n)) * 24 + (pp - PQq) * 3;
            o[0] = ox; o[1] = oy; o[2] = oz;
        }
    }
#pragma unroll
    for (int rep = 0; rep < 2; ++rep) {
        int idx = t + rep * 192;
        int h = idx / 32, c2 = idx % 32;
        int bh = b * Hh + h;
        float v = pr[192 + h * 32 + c2];
        if (c2 < 16) Kp[((size_t)(bh * Nn + n)) * 16 + c2] = v;
        else         Vp[((size_t)(bh * Nn + n)) * 16 + (c2 - 16)] = v;
    }
}

// ---------------- Kernel 3: attention v3 ----------------
// grid = B*H*24 = 1152 blocks, 256 threads (4 waves); 16 rows/block,
// wave covers 4 rows x 16 lanes; quad-transposed LDS tiles, b128 reads with
// 4-way same-address broadcast across row-groups; per-lane online softmax.
__global__ __launch_bounds__(256) void attn_kernel(
    const float* __restrict__ proj,
    const float* __restrict__ Kp, const float* __restrict__ Vp,
    const float* __restrict__ KPp, const float* __restrict__ VPp,
    const float* __restrict__ rot, const float* __restrict__ trans,
    const float* __restrict__ mask, const float* __restrict__ head_weights,
    float* __restrict__ cat)
{
    __shared__ float4 stK[4*JT];    // 8 KB   [c4][j]
    __shared__ float4 stKP[3*JT];   // 6 KB
    __shared__ float4 stV[4*JT];    // 8 KB
    __shared__ float4 stVP[6*JT];   // 12 KB
    __shared__ float  stM[Nn];      // 1.5 KB

    const int bid = blockIdx.x;
    const int ib = bid % 24;
    const int h  = (bid / 24) % Hh;
    const int b  = bid / (24 * Hh);
    const int tid = threadIdx.x;
    const int w = tid >> 6;
    const int lane = tid & 63;
    const int rg = lane >> 4;       // row-group 0..3
    const int jl = lane & 15;       // j-lane 0..15
    const int i = ib * 16 + w * 4 + rg;
    const int bnI = b * Nn + i;
    const int bh = b * Hh + h;

    for (int e = tid; e < Nn; e += 256) stM[e] = mask[b * Nn + e];

    // q row
    const float* qrow = proj + (size_t)bnI * FPROJ + h * Cc;
    float qv[16];
#pragma unroll
    for (int c = 0; c < 16; ++c) qv[c] = qrow[c];

    // q_pts rigid-apply
    const float* R = rot + (size_t)bnI * 9;
    const float* T = trans + (size_t)bnI * 3;
    float qpv[12];
    {
        const float* pq = proj + (size_t)bnI * FPROJ + 576;
#pragma unroll
        for (int p = 0; p < PQq; ++p) {
            float x = pq[h * PQq + p];
            float y = pq[48 + h * PQq + p];
            float z = pq[96 + h * PQq + p];
            qpv[p*3+0] = R[0]*x + R[1]*y + R[2]*z + T[0];
            qpv[p*3+1] = R[3]*x + R[4]*y + R[5]*z + T[1];
            qpv[p*3+2] = R[6]*x + R[7]*y + R[8]*z + T[2];
        }
    }

    const float hw = log1pf(expf(head_weights[h]));
    const float wc = -0.5f * hw * 0.13608276348795434f;   // * sqrt(1/54)
    const float scale2 = 2.0f * 0.14433756729740643f;     // 2 * sqrt(1/48)
    const float mi = mask[b * Nn + i];

    const float* KpB  = Kp  + (size_t)(bh * Nn) * 16;
    const float* VpB  = Vp  + (size_t)(bh * Nn) * 16;
    const float* KPpB = KPp + (size_t)(bh * Nn) * 12;
    const float* VPpB = VPp + (size_t)(bh * Nn) * 24;

    float m = -3.0e38f, ssum = 0.0f;
    float acc[16]; float accp[24];
#pragma unroll
    for (int c = 0; c < 16; ++c) acc[c] = 0.0f;
#pragma unroll
    for (int tt = 0; tt < 24; ++tt) accp[tt] = 0.0f;

    for (int tile = 0; tile < Nn / JT; ++tile) {
        const int jb = tile * JT;
        // ---- stage K (512 f4), V (512 f4) dense; KP (384 f4), VP (768 f4) ch-major ----
#pragma unroll
        for (int k = 0; k < 2; ++k) {
            int e = tid + k * 256;
            int j = e >> 2, c4 = e & 3;
            stK[c4 * JT + j] = *(const float4*)(KpB + ((size_t)(jb + j)) * 16 + c4 * 4);
            stV[c4 * JT + j] = *(const float4*)(VpB + ((size_t)(jb + j)) * 16 + c4 * 4);
        }
        {
            int e = tid;
            int cp = e >> 7, j = e & 127;
            stKP[cp * JT + j] = *(const float4*)(KPpB + ((size_t)(jb + j)) * 12 + cp * 4);
        }
        if (tid < 128) {
            int e = tid + 256;
            int cp = e >> 7, j = e & 127;
            stKP[cp * JT + j] = *(const float4*)(KPpB + ((size_t)(jb + j)) * 12 + cp * 4);
        }
#pragma unroll
        for (int k = 0; k < 3; ++k) {
            int e = tid + k * 256;
            int cp = e >> 7, j = e & 127;
            stVP[cp * JT + j] = *(const float4*)(VPpB + ((size_t)(jb + j)) * 24 + cp * 4);
        }
        __syncthreads();

        // ---- phase A: logits ----
        float lgv[8];
        float tmax = -3.0e38f;
#pragma unroll
        for (int jj = 0; jj < 8; ++jj) {
            int j16 = jj * 16 + jl;
            float4 k0 = stK[j16], k1 = stK[JT + j16], k2 = stK[2*JT + j16], k3 = stK[3*JT + j16];
            float dot = qv[0]*k0.x + qv[1]*k0.y + qv[2]*k0.z + qv[3]*k0.w
                      + qv[4]*k1.x + qv[5]*k1.y + qv[6]*k1.z + qv[7]*k1.w
                      + qv[8]*k2.x + qv[9]*k2.y + qv[10]*k2.z + qv[11]*k2.w
                      + qv[12]*k3.x + qv[13]*k3.y + qv[14]*k3.z + qv[15]*k3.w;
            float4 p0 = stKP[j16], p1 = stKP[JT + j16], p2 = stKP[2*JT + j16];
            float d0 = qpv[0]-p0.x, d1 = qpv[1]-p0.y, d2 = qpv[2]-p0.z, d3 = qpv[3]-p0.w;
            float d4 = qpv[4]-p1.x, d5 = qpv[5]-p1.y, d6 = qpv[6]-p1.z, d7 = qpv[7]-p1.w;
            float d8 = qpv[8]-p2.x, d9 = qpv[9]-p2.y, d10 = qpv[10]-p2.z, d11 = qpv[11]-p2.w;
            float sq = d0*d0 + d1*d1 + d2*d2 + d3*d3 + d4*d4 + d5*d5
                     + d6*d6 + d7*d7 + d8*d8 + d9*d9 + d10*d10 + d11*d11;
            float lgt = scale2 * dot + wc * sq + INFV * (mi * stM[jb + j16] - 1.0f);
            lgv[jj] = lgt;
            tmax = fmaxf(tmax, lgt);
        }

        // ---- phase B: rescale + accumulate ----
        {
            float mnew = fmaxf(m, tmax);
            float f = __expf(m - mnew);
            m = mnew;
            ssum *= f;
#pragma unroll
            for (int c = 0; c < 16; ++c) acc[c] *= f;
#pragma unroll
            for (int tt = 0; tt < 24; ++tt) accp[tt] *= f;
        }
#pragma unroll
        for (int jj = 0; jj < 8; ++jj) {
            int j16 = jj * 16 + jl;
            float a = __expf(lgv[jj] - m);
            ssum += a;
            float4 v0 = stV[j16], v1 = stV[JT + j16], v2 = stV[2*JT + j16], v3 = stV[3*JT + j16];
            acc[0] += a*v0.x; acc[1] += a*v0.y; acc[2] += a*v0.z; acc[3] += a*v0.w;
            acc[4] += a*v1.x; acc[5] += a*v1.y; acc[6] += a*v1.z; acc[7] += a*v1.w;
            acc[8] += a*v2.x; acc[9] += a*v2.y; acc[10] += a*v2.z; acc[11] += a*v2.w;
            acc[12] += a*v3.x; acc[13] += a*v3.y; acc[14] += a*v3.z; acc[15] += a*v3.w;
            float4 q0 = stVP[j16], q1 = stVP[JT + j16], q2 = stVP[2*JT + j16];
            float4 q3 = stVP[3*JT + j16], q4 = stVP[4*JT + j16], q5 = stVP[5*JT + j16];
            accp[0] += a*q0.x; accp[1] += a*q0.y; accp[2] += a*q0.z; accp[3] += a*q0.w;
            accp[4] += a*q1.x; accp[5] += a*q1.y; accp[6] += a*q1.z; accp[7] += a*q1.w;
            accp[8] += a*q2.x; accp[9] += a*q2.y; accp[10] += a*q2.z; accp[11] += a*q2.w;
            accp[12] += a*q3.x; accp[13] += a*q3.y; accp[14] += a*q3.z; accp[15] += a*q3.w;
            accp[16] += a*q4.x; accp[17] += a*q4.y; accp[18] += a*q4.z; accp[19] += a*q4.w;
            accp[20] += a*q5.x; accp[21] += a*q5.y; accp[22] += a*q5.z; accp[23] += a*q5.w;
        }
        __syncthreads();
    }

    // ---- cross-lane reduce within 16-lane groups ----
    float M = m;
#pragma unroll
    for (int off = 8; off >= 1; off >>= 1) M = fmaxf(M, __shfl_xor(M, off));
    {
        float f = __expf(m - M);
        ssum *= f;
#pragma unroll
        for (int c = 0; c < 16; ++c) acc[c] *= f;
#pragma unroll
        for (int tt = 0; tt < 24; ++tt) accp[tt] *= f;
    }
#pragma unroll
    for (int off = 8; off >= 1; off >>= 1) {
        ssum += __shfl_xor(ssum, off);
#pragma unroll
        for (int c = 0; c < 16; ++c) acc[c] += __shfl_xor(acc[c], off);
#pragma unroll
        for (int tt = 0; tt < 24; ++tt) accp[tt] += __shfl_xor(accp[tt], off);
    }

    const float inv = 1.0f / ssum;
    float* crow = cat + (size_t)bnI * FCAT;

    if (jl < 16) crow[h * 16 + jl] = acc[jl] * inv;
    if (jl < 8) {
        int p = jl;
        float g0 = accp[p*3+0] * inv - T[0];
        float g1 = accp[p*3+1] * inv - T[1];
        float g2 = accp[p*3+2] * inv - T[2];
        float lx = R[0]*g0 + R[3]*g1 + R[6]*g2;
        float ly = R[1]*g0 + R[4]*g1 + R[7]*g2;
        float lz = R[2]*g0 + R[5]*g1 + R[8]*g2;
        crow[192 + h*8 + p] = lx;
        crow[288 + h*8 + p] = ly;
        crow[384 + h*8 + p] = lz;
        crow[480 + h*8 + p] = sqrtf(lx*lx + ly*ly + lz*lz + EPSV);
    }
}

// ---------------- Kernel 4: output GEMM (scalar-cat, no LDS) ----------------
__global__ __launch_bounds__(384) void out_kernel(
    const float* __restrict__ cat,
    const float* __restrict__ w_out, const float* __restrict__ b_out,
    float* __restrict__ out)
{
    const int row0 = blockIdx.x * 6;
    const int t = threadIdx.x;
    float acc[6] = {0,0,0,0,0,0};
    const float* wp = w_out + t;
    const float* c0 = cat + (size_t)row0 * FCAT;
    for (int d = 0; d < FCAT; d += 4) {
        float4 cv[6];
#pragma unroll
        for (int r = 0; r < 6; ++r)
            cv[r] = *(const float4*)(c0 + (size_t)r * FCAT + d);   // uniform -> s_load
#pragma unroll
        for (int dd = 0; dd < 4; ++dd) {
            float wv = wp[(size_t)(d + dd) * 384];
#pragma unroll
            for (int r = 0; r < 6; ++r) acc[r] += ((const float*)&cv[r])[dd] * wv;
        }
    }
    const float bb = b_out[t];
#pragma unroll
    for (int r = 0; r < 6; ++r) out[(size_t)(row0 + r) * 384 + t] = acc[r] + bb;
}

extern "C" void kernel_launch(void* const* d_in, const int* in_sizes, int n_in,
                              void* d_out, int out_size, void* d_ws, size_t ws_size,
                              hipStream_t stream) {
    const float* s     = (const float*)d_in[0];
    const float* rot   = (const float*)d_in[2];
    const float* trans = (const float*)d_in[3];
    const float* mask  = (const float*)d_in[4];
    const float* w_q   = (const float*)d_in[5];
    const float* b_q   = (const float*)d_in[6];
    const float* w_kv  = (const float*)d_in[7];
    const float* b_kv  = (const float*)d_in[8];
    const float* w_qp  = (const float*)d_in[13];
    const float* b_qp  = (const float*)d_in[14];
    const float* w_kvp = (const float*)d_in[15];
    const float* b_kvp = (const float*)d_in[16];
    const float* hwts  = (const float*)d_in[17];
    const float* w_out = (const float*)d_in[18];
    const float* b_out = (const float*)d_in[19];

    float* ws    = (float*)d_ws;
    float* proj  = ws + WS_PROJ;
    float* Kp    = ws + WS_KP;
    float* Vp    = ws + WS_VP;
    float* KPp   = ws + WS_KPP;
    float* VPp   = ws + WS_VPP;
    float* catb  = ws + WS_CAT;
    float* out   = (float*)d_out;

    hipLaunchKernelGGL(proj_kernel, dim3(192), dim3(384), 0, stream,
                       s, w_q, b_q, w_kv, b_kv, w_qp, b_qp, w_kvp, b_kvp, proj);
    hipLaunchKernelGGL(pack_kernel, dim3(1536), dim3(192), 0, stream,
                       proj, rot, trans, Kp, Vp, KPp, VPp);
    hipLaunchKernelGGL(attn_kernel, dim3(1152), dim3(256), 0, stream,
                       proj, Kp, Vp, KPp, VPp, rot, trans, mask, hwts, catb);
    hipLaunchKernelGGL(out_kernel, dim3(256), dim3(384), 0, stream,
                       catb, w_out, b_out, out);
}